// Round 11
// baseline (56.338 us; speedup 1.0000x reference)
//
#include <hip/hip_runtime.h>

namespace {
constexpr int kB = 32;
constexpr int kS = 2048;
constexpr int kH = 1024;
constexpr int kD = 1024;
constexpr int kK2 = kH + kD;        // 2048
constexpr float kWThresh = 1e-8f;   // skipped weight mass <= 2048e-8 -> err ~1e-3 << 2e-2

typedef float f32x4 __attribute__((ext_vector_type(4)));

__device__ inline float waveReduceSum(float v) {
#pragma unroll
  for (int off = 32; off > 0; off >>= 1) v += __shfl_down(v, off, 64);
  return v;
}
__device__ inline float waveReduceMax(float v) {
#pragma unroll
  for (int off = 32; off > 0; off >>= 1) v = fmaxf(v, __shfl_down(v, off, 64));
  return v;
}
}  // namespace

// K1: x = hidden @ W1^T and pb = hidden @ W2[:, H:]^T (both [B, D]). (R9/R10 body)
__global__ __launch_bounds__(256) void k_gemv1(const float* __restrict__ hidden,
                                               const float* __restrict__ W1,
                                               const float* __restrict__ W2,
                                               float* __restrict__ x,
                                               float* __restrict__ pb) {
  const int wid_all = blockIdx.x * 4 + (threadIdx.x >> 6);  // 0..4095
  const int lane = threadIdx.x & 63;
  const bool isX = wid_all < 2048;
  const int wid = wid_all & 2047;
  const int n0 = (wid & 511) * 2;
  const int b0 = (wid >> 9) * 8;
  const float* wbase = isX ? (W1 + (size_t)n0 * kH) : (W2 + (size_t)n0 * kK2 + kH);
  const size_t wstride = isX ? (size_t)kH : (size_t)kK2;
  float* dst = isX ? x : pb;
  const f32x4* w0v = (const f32x4*)(wbase) + lane;
  const f32x4* w1v = (const f32x4*)(wbase + wstride) + lane;
  f32x4 w0[4], w1[4];
#pragma unroll
  for (int i = 0; i < 4; ++i) { w0[i] = w0v[64 * i]; w1[i] = w1v[64 * i]; }
  for (int b = b0; b < b0 + 8; ++b) {
    const f32x4* hv = (const f32x4*)(hidden + (size_t)b * kH) + lane;
    f32x4 s0v = {0.f, 0.f, 0.f, 0.f}, s1v = {0.f, 0.f, 0.f, 0.f};
#pragma unroll
    for (int i = 0; i < 4; ++i) {
      const f32x4 h = hv[64 * i];
      s0v += w0[i] * h;
      s1v += w1[i] * h;
    }
    const float a0 = waveReduceSum(s0v.x + s0v.y + s0v.z + s0v.w);
    const float a1 = waveReduceSum(s1v.x + s1v.y + s1v.z + s1v.w);
    if (lane == 0) {
      dst[(size_t)b * kD + n0] = a0;
      dst[(size_t)b * kD + n0 + 1] = a1;
    }
  }
}

// K2: att[b,s] = enc[b,s,:] . x[b,:] for s < len[b]. 8 rows/wave; loads
// interleaved across rows (8 KB/wave in flight per d-chunk step), ALL reduces
// deferred to the end as 8 independent pipelined butterflies.
__global__ __launch_bounds__(256) void k_att(const float* __restrict__ enc,
                                             const float* __restrict__ x,
                                             const int* __restrict__ lens,
                                             float* __restrict__ att) {
  const int lane = threadIdx.x & 63;
  const int wib = threadIdx.x >> 6;
  const int b = blockIdx.x & 31;
  const int s0 = (blockIdx.x >> 5) * 32;  // 32 rows per block
  const int len = lens[b];
  if (s0 >= len) return;                  // weights exactly 0 -> never needed
  const int rs0 = s0 + wib * 8;           // 8 rows per wave
  if (rs0 >= len) return;
  const f32x4* xv = (const f32x4*)(x + (size_t)b * kD) + lane;
  f32x4 xr[4];
#pragma unroll
  for (int i = 0; i < 4; ++i) xr[i] = xv[64 * i];
  const float* eb = enc + ((size_t)b * kS + rs0) * kD;
  float d[8];
#pragma unroll
  for (int r = 0; r < 8; ++r) d[r] = 0.f;
#pragma unroll
  for (int i = 0; i < 4; ++i) {
#pragma unroll
    for (int r = 0; r < 8; ++r) {
      const f32x4 e = *((const f32x4*)(eb + (size_t)r * kD) + lane + 64 * i);
      d[r] += e.x * xr[i].x + e.y * xr[i].y + e.z * xr[i].z + e.w * xr[i].w;
    }
  }
  // 8 independent butterflies: shuffles pipeline across r, ~1 chain latency total
#pragma unroll
  for (int off = 32; off > 0; off >>= 1) {
#pragma unroll
    for (int r = 0; r < 8; ++r) d[r] += __shfl_down(d[r], off, 64);
  }
  if (lane == 0) {
    f32x4 o0, o1;
    o0.x = d[0]; o0.y = d[1]; o0.z = d[2]; o0.w = d[3];
    o1.x = d[4]; o1.y = d[5]; o1.z = d[6]; o1.w = d[7];
    *(f32x4*)(att + (size_t)b * kS + rs0) = o0;      // rows >= len: garbage, never read
    *(f32x4*)(att + (size_t)b * kS + rs0 + 4) = o1;
  }
}

// K34: fused masked softmax (==0 -> -1e10 quirk) + attnT + survivor ctx + out.
// (R10 body, unchanged)
__global__ __launch_bounds__(256) void k_smout(const float* __restrict__ att,
                                               const int* __restrict__ lens,
                                               const float* __restrict__ enc,
                                               const float* __restrict__ pb,
                                               const float* __restrict__ W2,
                                               float* __restrict__ attnT,
                                               float* __restrict__ out) {
  const int b = blockIdx.x & 31;
  const int sub = blockIdx.x >> 5;  // 0..15: which 64-column slice of out
  const int t = threadIdx.x;
  const int lane = t & 63;
  const int wib = t >> 6;
  const int len = lens[b];
  __shared__ float sred[4];
  __shared__ float swts[kS];
  __shared__ int sidx[kS];
  __shared__ int scount;
  __shared__ float ctx_lds[kD];

  float v[8];
#pragma unroll
  for (int i = 0; i < 8; ++i) {
    const int s = t + i * 256;
    float a = -1e10f;
    if (s < len) {
      const float av = att[(size_t)b * kS + s];
      a = (av == 0.0f) ? -1e10f : av;  // faithful ==0 -> -1e10 quirk
    }
    v[i] = a;
  }
  float m = v[0];
#pragma unroll
  for (int i = 1; i < 8; ++i) m = fmaxf(m, v[i]);
  m = waveReduceMax(m);
  if (lane == 0) sred[wib] = m;
  __syncthreads();
  m = fmaxf(fmaxf(sred[0], sred[1]), fmaxf(sred[2], sred[3]));
  __syncthreads();
  float p[8];
  float sum = 0.f;
#pragma unroll
  for (int i = 0; i < 8; ++i) {
    p[i] = __expf(v[i] - m);  // exactly 0 for masked rows (non-degenerate)
    sum += p[i];
  }
  sum = waveReduceSum(sum);
  if (lane == 0) sred[wib] = sum;
  __syncthreads();
  const float inv = 1.0f / (sred[0] + sred[1] + sred[2] + sred[3]);
  if (t == 0) scount = 0;
  __syncthreads();
#pragma unroll
  for (int i = 0; i < 8; ++i) {
    const int s = t + i * 256;
    const float w = p[i] * inv;
    if (sub == 0) attnT[(size_t)s * kB + b] = w;  // output 1: attn^T [S][B]
    if (w > kWThresh) {
      const int k = atomicAdd(&scount, 1);
      sidx[k] = s;
      swts[k] = w;
    }
  }
  __syncthreads();

  const int n = scount;
  const float* ebase = enc + (size_t)b * kS * kD + t;
  float acc0 = 0.f, acc1 = 0.f, acc2 = 0.f, acc3 = 0.f;
  for (int k = 0; k < n; ++k) {
    const float w = swts[k];
    const float* row = ebase + (size_t)sidx[k] * kD;
    acc0 += w * row[0];
    acc1 += w * row[256];
    acc2 += w * row[512];
    acc3 += w * row[768];
  }
  ctx_lds[t] = acc0;
  ctx_lds[t + 256] = acc1;
  ctx_lds[t + 512] = acc2;
  ctx_lds[t + 768] = acc3;
  __syncthreads();

  f32x4 c[4];
  const f32x4* cl = (const f32x4*)ctx_lds + lane;
#pragma unroll
  for (int i = 0; i < 4; ++i) c[i] = cl[64 * i];
#pragma unroll
  for (int j = 0; j < 8; ++j) {
    const int n0 = sub * 64 + wib * 16 + j * 2;
    const f32x4* w0v = (const f32x4*)(W2 + (size_t)n0 * kK2) + lane;
    const f32x4* w1v = (const f32x4*)(W2 + (size_t)(n0 + 1) * kK2) + lane;
    f32x4 s0v = {0.f, 0.f, 0.f, 0.f}, s1v = {0.f, 0.f, 0.f, 0.f};
#pragma unroll
    for (int i = 0; i < 4; ++i) {
      s0v += w0v[64 * i] * c[i];
      s1v += w1v[64 * i] * c[i];
    }
    const float a0 = waveReduceSum(s0v.x + s0v.y + s0v.z + s0v.w);
    const float a1 = waveReduceSum(s1v.x + s1v.y + s1v.z + s1v.w);
    if (lane == 0) {
      out[(size_t)b * kD + n0] = tanhf(a0 + pb[(size_t)b * kD + n0]);
      out[(size_t)b * kD + n0 + 1] = tanhf(a1 + pb[(size_t)b * kD + n0 + 1]);
    }
  }
}

extern "C" void kernel_launch(void* const* d_in, const int* in_sizes, int n_in,
                              void* d_out, int out_size, void* d_ws, size_t ws_size,
                              hipStream_t stream) {
  const float* hidden = (const float*)d_in[0];  // [B, H]
  const float* enc    = (const float*)d_in[1];  // [B, S, D]
  const int*   lens   = (const int*)d_in[2];    // [B]
  const float* W1     = (const float*)d_in[3];  // [D, H]
  const float* W2     = (const float*)d_in[4];  // [D, H+D]

  float* out   = (float*)d_out;          // [B, D]
  float* attnT = out + (size_t)kB * kD;  // [S, B]

  float* ws  = (float*)d_ws;
  float* x   = ws;              // 32768
  float* att = ws + 32768;      // 65536
  float* pb  = ws + 98304;      // 32768

  k_gemv1<<<1024, 256, 0, stream>>>(hidden, W1, W2, x, pb);
  k_att<<<kB * (kS / 32), 256, 0, stream>>>(enc, x, lens, att);
  k_smout<<<kB * 16, 256, 0, stream>>>(att, lens, enc, pb, W2, attnT, out);
}

// Round 12
// 54.872 us; speedup vs baseline: 1.0267x; 1.0267x over previous
//
#include <hip/hip_runtime.h>

namespace {
constexpr int kB = 32;
constexpr int kS = 2048;
constexpr int kH = 1024;
constexpr int kD = 1024;
constexpr int kK2 = kH + kD;        // 2048
constexpr float kWThresh = 1e-8f;   // skipped weight mass <= 2048e-8 -> err ~1e-3 << 2e-2

typedef float f32x4 __attribute__((ext_vector_type(4)));

__device__ inline float waveReduceSum(float v) {
#pragma unroll
  for (int off = 32; off > 0; off >>= 1) v += __shfl_down(v, off, 64);
  return v;
}
__device__ inline float waveReduceMax(float v) {
#pragma unroll
  for (int off = 32; off > 0; off >>= 1) v = fmaxf(v, __shfl_down(v, off, 64));
  return v;
}
}  // namespace

// K1: x = hidden @ W1^T and pb = hidden @ W2[:, H:]^T (both [B, D]). (R9/R10 body)
__global__ __launch_bounds__(256) void k_gemv1(const float* __restrict__ hidden,
                                               const float* __restrict__ W1,
                                               const float* __restrict__ W2,
                                               float* __restrict__ x,
                                               float* __restrict__ pb) {
  const int wid_all = blockIdx.x * 4 + (threadIdx.x >> 6);  // 0..4095
  const int lane = threadIdx.x & 63;
  const bool isX = wid_all < 2048;
  const int wid = wid_all & 2047;
  const int n0 = (wid & 511) * 2;
  const int b0 = (wid >> 9) * 8;
  const float* wbase = isX ? (W1 + (size_t)n0 * kH) : (W2 + (size_t)n0 * kK2 + kH);
  const size_t wstride = isX ? (size_t)kH : (size_t)kK2;
  float* dst = isX ? x : pb;
  const f32x4* w0v = (const f32x4*)(wbase) + lane;
  const f32x4* w1v = (const f32x4*)(wbase + wstride) + lane;
  f32x4 w0[4], w1[4];
#pragma unroll
  for (int i = 0; i < 4; ++i) { w0[i] = w0v[64 * i]; w1[i] = w1v[64 * i]; }
  for (int b = b0; b < b0 + 8; ++b) {
    const f32x4* hv = (const f32x4*)(hidden + (size_t)b * kH) + lane;
    f32x4 s0v = {0.f, 0.f, 0.f, 0.f}, s1v = {0.f, 0.f, 0.f, 0.f};
#pragma unroll
    for (int i = 0; i < 4; ++i) {
      const f32x4 h = hv[64 * i];
      s0v += w0[i] * h;
      s1v += w1[i] * h;
    }
    const float a0 = waveReduceSum(s0v.x + s0v.y + s0v.z + s0v.w);
    const float a1 = waveReduceSum(s1v.x + s1v.y + s1v.z + s1v.w);
    if (lane == 0) {
      dst[(size_t)b * kD + n0] = a0;
      dst[(size_t)b * kD + n0 + 1] = a1;
    }
  }
}

// K2: att[b,s] = enc[b,s,:] . x[b,:] for s < len[b]. (R10 body: 4 rows/wave,
// plain loads, f32x4 score store — best-measured variant.)
__global__ __launch_bounds__(256) void k_att(const float* __restrict__ enc,
                                             const float* __restrict__ x,
                                             const int* __restrict__ lens,
                                             float* __restrict__ att) {
  const int lane = threadIdx.x & 63;
  const int wib = threadIdx.x >> 6;
  const int b = blockIdx.x & 31;
  const int s0 = (blockIdx.x >> 5) * 16 + wib * 4;
  const int len = lens[b];
  if (s0 >= len) return;  // weights exactly 0 -> scores never needed
  const f32x4* xv = (const f32x4*)(x + (size_t)b * kD) + lane;
  f32x4 xr[4];
#pragma unroll
  for (int i = 0; i < 4; ++i) xr[i] = xv[64 * i];
  float acc[4];
#pragma unroll
  for (int r = 0; r < 4; ++r) {
    const f32x4* ev = (const f32x4*)(enc + ((size_t)b * kS + s0 + r) * kD) + lane;
    f32x4 d = {0.f, 0.f, 0.f, 0.f};
#pragma unroll
    for (int i = 0; i < 4; ++i) {
      const f32x4 e = ev[64 * i];
      d += e * xr[i];
    }
    acc[r] = waveReduceSum(d.x + d.y + d.z + d.w);
  }
  if (lane == 0) {
    f32x4 o;
    o.x = acc[0]; o.y = acc[1]; o.z = acc[2]; o.w = acc[3];
    *(f32x4*)(att + (size_t)b * kS + s0) = o;  // rows >= len: garbage, never read
  }
}

// K34: fused masked softmax (==0 -> -1e10 quirk) + attnT + survivor ctx + out.
// XCD-aware mapping: all 32 blocks sharing a W2a column-slice (same sub) land
// on the same XCD (blockIdx % 8 fixed), so its L2 serves 31/32 W2a reads.
__global__ __launch_bounds__(256) void k_smout(const float* __restrict__ att,
                                               const int* __restrict__ lens,
                                               const float* __restrict__ enc,
                                               const float* __restrict__ pb,
                                               const float* __restrict__ W2,
                                               float* __restrict__ attnT,
                                               float* __restrict__ out) {
  const int b = blockIdx.x >> 4;                                   // 0..31
  const int sub = ((blockIdx.x & 7) << 1) | ((blockIdx.x >> 3) & 1);  // 0..15, XCD-clustered
  const int t = threadIdx.x;
  const int lane = t & 63;
  const int wib = t >> 6;
  const int len = lens[b];
  __shared__ float sred[4];
  __shared__ float swts[kS];
  __shared__ int sidx[kS];
  __shared__ int scount;
  __shared__ float ctx_lds[kD];

  // ---- softmax over att[b][:] (8 scores per thread)
  float v[8];
#pragma unroll
  for (int i = 0; i < 8; ++i) {
    const int s = t + i * 256;
    float a = -1e10f;
    if (s < len) {
      const float av = att[(size_t)b * kS + s];
      a = (av == 0.0f) ? -1e10f : av;  // faithful ==0 -> -1e10 quirk
    }
    v[i] = a;
  }
  float m = v[0];
#pragma unroll
  for (int i = 1; i < 8; ++i) m = fmaxf(m, v[i]);
  m = waveReduceMax(m);
  if (lane == 0) sred[wib] = m;
  __syncthreads();
  m = fmaxf(fmaxf(sred[0], sred[1]), fmaxf(sred[2], sred[3]));
  __syncthreads();
  float p[8];
  float sum = 0.f;
#pragma unroll
  for (int i = 0; i < 8; ++i) {
    p[i] = __expf(v[i] - m);  // exactly 0 for masked rows (non-degenerate)
    sum += p[i];
  }
  sum = waveReduceSum(sum);
  if (lane == 0) sred[wib] = sum;
  __syncthreads();
  const float inv = 1.0f / (sred[0] + sred[1] + sred[2] + sred[3]);
  if (t == 0) scount = 0;
  __syncthreads();
#pragma unroll
  for (int i = 0; i < 8; ++i) {
    const int s = t + i * 256;
    const float w = p[i] * inv;
    if (sub == 0) attnT[(size_t)s * kB + b] = w;  // output 1: attn^T [S][B]
    if (w > kWThresh) {
      const int k = atomicAdd(&scount, 1);
      sidx[k] = s;
      swts[k] = w;
    }
  }
  __syncthreads();

  // ---- ctx gather into LDS (thread t owns d = t, t+256, t+512, t+768)
  const int n = scount;
  const float* ebase = enc + (size_t)b * kS * kD + t;
  float acc0 = 0.f, acc1 = 0.f, acc2 = 0.f, acc3 = 0.f;
  for (int k = 0; k < n; ++k) {
    const float w = swts[k];
    const float* row = ebase + (size_t)sidx[k] * kD;
    acc0 += w * row[0];
    acc1 += w * row[256];
    acc2 += w * row[512];
    acc3 += w * row[768];
  }
  ctx_lds[t] = acc0;
  ctx_lds[t + 256] = acc1;
  ctx_lds[t + 512] = acc2;
  ctx_lds[t + 768] = acc3;
  __syncthreads();

  // ---- out slice: cols sub*64 .. sub*64+63; wave wib does 16 cols (8 pairs)
  f32x4 c[4];
  const f32x4* cl = (const f32x4*)ctx_lds + lane;
#pragma unroll
  for (int i = 0; i < 4; ++i) c[i] = cl[64 * i];
#pragma unroll
  for (int j = 0; j < 8; ++j) {
    const int n0 = sub * 64 + wib * 16 + j * 2;
    const f32x4* w0v = (const f32x4*)(W2 + (size_t)n0 * kK2) + lane;
    const f32x4* w1v = (const f32x4*)(W2 + (size_t)(n0 + 1) * kK2) + lane;
    f32x4 s0v = {0.f, 0.f, 0.f, 0.f}, s1v = {0.f, 0.f, 0.f, 0.f};
#pragma unroll
    for (int i = 0; i < 4; ++i) {
      s0v += w0v[64 * i] * c[i];
      s1v += w1v[64 * i] * c[i];
    }
    const float a0 = waveReduceSum(s0v.x + s0v.y + s0v.z + s0v.w);
    const float a1 = waveReduceSum(s1v.x + s1v.y + s1v.z + s1v.w);
    if (lane == 0) {
      out[(size_t)b * kD + n0] = tanhf(a0 + pb[(size_t)b * kD + n0]);
      out[(size_t)b * kD + n0 + 1] = tanhf(a1 + pb[(size_t)b * kD + n0 + 1]);
    }
  }
}

extern "C" void kernel_launch(void* const* d_in, const int* in_sizes, int n_in,
                              void* d_out, int out_size, void* d_ws, size_t ws_size,
                              hipStream_t stream) {
  const float* hidden = (const float*)d_in[0];  // [B, H]
  const float* enc    = (const float*)d_in[1];  // [B, S, D]
  const int*   lens   = (const int*)d_in[2];    // [B]
  const float* W1     = (const float*)d_in[3];  // [D, H]
  const float* W2     = (const float*)d_in[4];  // [D, H+D]

  float* out   = (float*)d_out;          // [B, D]
  float* attnT = out + (size_t)kB * kD;  // [S, B]

  float* ws  = (float*)d_ws;
  float* x   = ws;              // 32768
  float* att = ws + 32768;      // 65536
  float* pb  = ws + 98304;      // 32768

  k_gemv1<<<1024, 256, 0, stream>>>(hidden, W1, W2, x, pb);
  k_att<<<kB * (kS / 16), 256, 0, stream>>>(enc, x, lens, att);
  k_smout<<<kB * 16, 256, 0, stream>>>(att, lens, enc, pb, W2, attnT, out);
}